// Round 11
// baseline (1213.261 us; speedup 1.0000x reference)
//
#include <hip/hip_runtime.h>

// Decoder: h0 = latent@fc_W^T + fc_b ; 128-step LSTM with folded feedback
// (x_t = y_{t-1} folded into W_total = W_hh + W_ih@out_W) ; Y = H_hist@out_W^T + out_b.
// All fp16. k_persist runs ALL 128 steps. Round 11 geometry: 16 chains x 16 batch
// rows, 32 WGs/chain (WG = 16 rows x 128 permuted cols), 512 WGs = 2 WGs/CU from
// DIFFERENT chains (chain = wg>>5) -> chain-A RTT waits overlap chain-B compute.
// Sync protocol = round-4/9 proven: h stored sc0+sc1 into fresh Hh[t], vmcnt drain,
// WG flag sc0+sc1, wave0 polls 32 chain flags (dwordx4/lane). Staging of Hh[t-1]
// uses PLAIN CACHED global_load_lds (reads happen only after flags prove h@IC;
// fresh lines -> local L2 can only hold the fresh version; same-XCD chain WGs
// share staged lines). Row-major fp16 ws matrices "swz": (row,k) at k^((row&7)<<3).

typedef __attribute__((ext_vector_type(8))) _Float16 f16x8;
typedef __attribute__((ext_vector_type(4))) float f32x4;
typedef __attribute__((ext_vector_type(4))) unsigned u32x4;

#define MFMA16(a,b,c) __builtin_amdgcn_mfma_f32_16x16x32_f16(a,b,c,0,0,0)

__device__ __forceinline__ short f2h(float x){
  return __builtin_bit_cast(short, (_Float16)x);
}
__device__ __forceinline__ unsigned pack2h(float a, float b){
  unsigned short ua = __builtin_bit_cast(unsigned short, (_Float16)a);
  unsigned short ub = __builtin_bit_cast(unsigned short, (_Float16)b);
  return (unsigned)ua | ((unsigned)ub << 16);
}

__device__ __forceinline__ void gll16(const void* g, void* l){
  __builtin_amdgcn_global_load_lds((const __attribute__((address_space(1))) void*)g,
                                   (__attribute__((address_space(3))) void*)l, 16, 0, 0);
}

__device__ __forceinline__ void vm0(){ asm volatile("s_waitcnt vmcnt(0)" ::: "memory"); }

// stage a 64x64 fp16 tile (pre-swizzled global, row-major ld=ldk) into LDS (linear image)
__device__ __forceinline__ void stage_t(const short* gRC, int ldk, short* lds, int lane, int wv){
#pragma unroll
  for (int jj = 0; jj < 2; ++jj){
    int j = wv*2 + jj;
    const short* src = gRC + (size_t)(j*8 + (lane>>3))*ldk + ((lane&7)*8);
    gll16(src, lds + j*512);
  }
}

// MFMA A/B fragment from a 64x64 swizzled LDS tile image
__device__ __forceinline__ f16x8 fragh(const short* t, int r, int kk, int lane){
  int row = r + (lane & 15);
  int k0  = (kk<<5) + ((lane>>4)<<3);
  return *(const f16x8*)(t + row*64 + (k0 ^ ((row & 7)<<3)));
}

// generic 64x64-tile fp16 GEMM core, CH k-chunks of 64
template<int CH>
__device__ __forceinline__ void core_k(const short* Ag, const short* Bg, int ldk,
                                       short* As, short* Bs, f32x4 (&acc)[2][2],
                                       int lane, int wv, int wr, int wc){
  stage_t(Ag, ldk, As, lane, wv);
  stage_t(Bg, ldk, Bs, lane, wv);
  __syncthreads();
  int buf = 0;
  for (int c = 0; c < CH; ++c){
    if (c+1 < CH){
      stage_t(Ag + (c+1)*64, ldk, As + (buf^1)*4096, lane, wv);
      stage_t(Bg + (c+1)*64, ldk, Bs + (buf^1)*4096, lane, wv);
    }
    const short* At = As + buf*4096;
    const short* Bt = Bs + buf*4096;
#pragma unroll
    for (int kk = 0; kk < 2; ++kk){
      f16x8 a0 = fragh(At, wr,    kk, lane), a1 = fragh(At, wr+16, kk, lane);
      f16x8 b0 = fragh(Bt, wc,    kk, lane), b1 = fragh(Bt, wc+16, kk, lane);
      acc[0][0] = MFMA16(a0,b0,acc[0][0]); acc[0][1] = MFMA16(a0,b1,acc[0][1]);
      acc[1][0] = MFMA16(a1,b0,acc[1][0]); acc[1][1] = MFMA16(a1,b1,acc[1][1]);
    }
    __syncthreads();
    buf ^= 1;
  }
}

// ---------------- setup ----------------
// Weight frag-block layout: block(c,s) = 512 shorts at ((c*32)+s)*512 ; within:
// lane l covers (gatecol p = 16c + (l&15), k = 32s + (l>>4)*8 .. +8). p is the
// PERMUTED gate index p = ((r&1023)<<2) | (r>>10) (unit*4+gate, torch i,f,g,o).

__global__ void k_prep(const float* __restrict__ W_ih, const float* __restrict__ out_W,
                       const float* __restrict__ latent, const float* __restrict__ fc_W,
                       const float* __restrict__ W_hh,
                       const float* __restrict__ b_ih, const float* __restrict__ b_hh,
                       short* __restrict__ WihF, short* __restrict__ owT,
                       short* __restrict__ owB, short* __restrict__ latF,
                       short* __restrict__ fcwF, short* __restrict__ W0F,
                       float* __restrict__ bias0, unsigned* __restrict__ flags){
  int T = blockDim.x*gridDim.x, t0 = blockIdx.x*blockDim.x + threadIdx.x;
  for (int i = t0; i < 8192; i += T) flags[i] = 0u;
  for (int idx = t0; idx < 4096*256; idx += T){    // WihF [4096][256] swz
    int r = idx >> 8, j = idx & 255;
    WihF[(size_t)r*256 + (j ^ ((r&7)<<3))] = f2h(W_ih[idx]);
  }
  for (int idx = t0; idx < 1024*256; idx += T){    // owT [1024][256]: owT[c][j]=out_W[j][c]
    int c = idx >> 8, j = idx & 255;
    owT[(size_t)c*256 + (j ^ ((c&7)<<3))] = f2h(out_W[(size_t)j*1024 + c]);
  }
  for (int idx = t0; idx < 256*1024; idx += T){    // owB [256][1024] swz
    int o = idx >> 10, k = idx & 1023;
    owB[(size_t)o*1024 + (k ^ ((o&7)<<3))] = f2h(out_W[idx]);
  }
  for (int idx = t0; idx < 256*512; idx += T){     // latF [256][512] swz
    int b = idx >> 9, j = idx & 511;
    latF[(size_t)b*512 + (j ^ ((b&7)<<3))] = f2h(latent[idx]);
  }
  for (int idx = t0; idx < 1024*512; idx += T){    // fcwF [1024][512] swz
    int n = idx >> 9, j = idx & 511;
    fcwF[(size_t)n*512 + (j ^ ((n&7)<<3))] = f2h(fc_W[idx]);
  }
  for (int idx = t0; idx < 4096*1024; idx += T){   // W0F = fp16(W_hh) frag blocks
    int r = idx >> 10, k = idx & 1023;
    int p = ((r & 1023)<<2) | (r >> 10);
    size_t a = ((size_t)(p>>4)*32 + (k>>5))*512 + ((size_t)((((k>>3)&3)<<4)|(p&15)))*8 + (k&7);
    W0F[a] = f2h(W_hh[idx]);
  }
  for (int r = t0; r < 4096; r += T){
    int rp = ((r & 1023)<<2) | (r >> 10);
    bias0[rp] = b_ih[r] + b_hh[r];
  }
}

__global__ void k_bias1(const float* __restrict__ W_ih, const float* __restrict__ out_b,
                        const float* __restrict__ bias0, float* __restrict__ bias1){
  int r = blockIdx.x*256 + threadIdx.x;            // 4096 threads
  float s = 0.f;
  for (int j = 0; j < 256; ++j) s += W_ih[(size_t)r*256 + j]*out_b[j];
  int rp = ((r & 1023)<<2) | (r >> 10);
  bias1[rp] = bias0[rp] + s;
}

// WtF = fp16(W_hh + W_ih@out_W), frag-block layout
__global__ __launch_bounds__(256) void k_wtotal(const short* __restrict__ WihF,
                                                const short* __restrict__ owT,
                                                const float* __restrict__ W_hh,
                                                short* __restrict__ WtF){
  __shared__ __align__(16) short As[2*4096];
  __shared__ __align__(16) short Bs[2*4096];
  int tid = threadIdx.x, lane = tid & 63, wv = tid >> 6;
  int wr = (wv>>1)*32, wc = (wv&1)*32;
  int Rm = blockIdx.x*64, Rn = blockIdx.y*64;
  f32x4 acc[2][2] = {};
  core_k<4>(WihF + (size_t)Rm*256, owT + (size_t)Rn*256, 256, As, Bs, acc, lane, wv, wr, wc);
#pragma unroll
  for (int mi = 0; mi < 2; ++mi)
#pragma unroll
  for (int ni = 0; ni < 2; ++ni)
#pragma unroll
  for (int r = 0; r < 4; ++r){
    int row = Rm + wr + mi*16 + ((lane>>4)<<2) + r;   // gate row
    int col = Rn + wc + ni*16 + (lane & 15);          // k
    float v = acc[mi][ni][r] + W_hh[(size_t)row*1024 + col];
    int p = ((row & 1023)<<2) | (row >> 10);
    size_t a = ((size_t)(p>>4)*32 + (col>>5))*512 + ((size_t)((((col>>3)&3)<<4)|(p&15)))*8 + (col&7);
    WtF[a] = f2h(v);
  }
}

// h0 = latent@fc_W^T + fc_b -> A0 fp16 swz
__global__ __launch_bounds__(256) void k_h0(const short* __restrict__ latF,
                                            const short* __restrict__ fcwF,
                                            const float* __restrict__ fc_b,
                                            short* __restrict__ A0){
  __shared__ __align__(16) short As[2*4096];
  __shared__ __align__(16) short Bs[2*4096];
  int tid = threadIdx.x, lane = tid & 63, wv = tid >> 6;
  int wr = (wv>>1)*32, wc = (wv&1)*32;
  int Rm = blockIdx.x*64, Rn = blockIdx.y*64;
  f32x4 acc[2][2] = {};
  core_k<8>(latF + (size_t)Rm*512, fcwF + (size_t)Rn*512, 512, As, Bs, acc, lane, wv, wr, wc);
#pragma unroll
  for (int mi = 0; mi < 2; ++mi)
#pragma unroll
  for (int ni = 0; ni < 2; ++ni)
#pragma unroll
  for (int r = 0; r < 4; ++r){
    int row = Rm + wr + mi*16 + ((lane>>4)<<2) + r;   // batch
    int col = Rn + wc + ni*16 + (lane & 15);          // unit
    float h = acc[mi][ni][r] + fc_b[col];
    A0[(size_t)row*1024 + (col ^ ((row&7)<<3))] = f2h(h);
  }
}

// ---------------- persistent kernel: steps 0..127 ----------------
// 512 WGs x 512 thr. chain = wg>>5 (16 chains x 16 rows), gw = wg&31.
// WG: batch rows chain*16..+16, permuted gate cols gw*128..+128.
// Wave (wn=wv&3, kh=wv>>2): cols wn*32..+32 of WG block, k-half kh*512..+512.
// 2 WGs/CU (49.6 KB LDS each); co-resident pair (wg, wg+256) = chains differing
// by 8 -> independent recurrences overlap on the CU.
__global__ __launch_bounds__(512, 2) void k_persist(
    const short* __restrict__ WtF, const short* __restrict__ W0F,
    const float* __restrict__ bias0, const float* __restrict__ bias1,
    const short* __restrict__ A0, short* __restrict__ Hh,
    unsigned* __restrict__ flags){
  __shared__ __align__(16) short Asl[16*1024];      // 32 KB chain A slice (swz image)
  __shared__ __align__(16) float Lg0[16*132];       // kh=0 partial gates
  __shared__ __align__(16) float Lg1[16*132];       // kh=1 partial gates
  const int tid = threadIdx.x, lane = tid & 63, wv = tid >> 6;
  const int wg = blockIdx.x;
  const int chain = wg >> 5, gw = wg & 31;
  const int wn = wv & 3, kh = wv >> 2;
  const int cbase = gw*8 + wn*2, sbase = kh*16;

  // one-time agent-acquire: invalidate local caches (prior-replay residue)
  __builtin_amdgcn_fence(__ATOMIC_ACQUIRE, "agent");

  // W_total fragments (compiler keeps or re-streams from L2 — proven either way)
  f16x8 Breg[2][16];
  {
    const short* src = WtF + ((size_t)cbase*32 + sbase)*512 + lane*8;
#pragma unroll
    for (int cf = 0; cf < 2; ++cf)
#pragma unroll
      for (int s = 0; s < 16; ++s)
        Breg[cf][s] = *(const f16x8*)(src + (size_t)(cf*32 + s)*512);
  }
  const short* W0base = W0F + ((size_t)cbase*32 + sbase)*512 + lane*8;

  // A-frag addressing
  const int r0 = lane & 15;
  const int kql = (lane>>4)<<3;
  const int sw = (r0 & 7) << 3;

  // cell phase (tid<256): thread (er,up) owns row er, units 2up,2up+1 of this WG
  const int er = tid >> 4, up = tid & 15;           // er<16 valid only for tid<256
  const int grow = chain*16 + (er & 15);
  const int swE = (grow & 7) << 3;
  const int posE = (gw*32 + 2*up) ^ swE;            // pair stays adjacent, 4B aligned
  const f32x4 b1qA = *(const f32x4*)(bias1 + gw*128 + 8*up);
  const f32x4 b1qB = *(const f32x4*)(bias1 + gw*128 + 8*up + 4);
  float cA = 0.f, cB = 0.f;

  unsigned* flagC = flags + (size_t)chain*64;       // this chain's 32-flag line (128B)

  for (int t = 0; t < 128; ++t){
    // ---- stage chain A slice (16 rows, 32 KB) with plain cached global_load_lds ----
    {
      const short* base = (t == 0) ? A0 : (Hh + (size_t)(t-1)*262144);
      const short* bb = base + (size_t)(chain*16)*1024;
#pragma unroll
      for (int q = 0; q < 4; ++q){
        int i = wv*4 + q;                            // 32 chunks of 1KB
        gll16(bb + (size_t)(i>>1)*1024 + (i&1)*512 + lane*8, Asl + i*512);
      }
    }
    __syncthreads();                                 // B1: Asl ready (drains lds-dma)

    f32x4 acc[2] = {};
    const short* Ar0 = Asl + r0*1024;
    if (t == 0){
#pragma unroll
      for (int s = 0; s < 16; ++s){
        int k = (sbase + s)*32 + kql;
        f16x8 w0 = *(const f16x8*)(W0base + (size_t)(0*32 + s)*512);
        f16x8 w1 = *(const f16x8*)(W0base + (size_t)(1*32 + s)*512);
        f16x8 a0 = *(const f16x8*)(Ar0 + (k ^ sw));
        acc[0] = MFMA16(a0, w0, acc[0]);
        acc[1] = MFMA16(a0, w1, acc[1]);
      }
    } else {
#pragma unroll
      for (int s = 0; s < 16; ++s){
        int k = (sbase + s)*32 + kql;
        f16x8 a0 = *(const f16x8*)(Ar0 + (k ^ sw));
        acc[0] = MFMA16(a0, Breg[0][s], acc[0]);
        acc[1] = MFMA16(a0, Breg[1][s], acc[1]);
      }
    }
    // ---- partial gates -> LDS (kh halves in Lg0/Lg1) ----
    {
      float* Lg = kh ? Lg1 : Lg0;
#pragma unroll
      for (int cf = 0; cf < 2; ++cf)
#pragma unroll
      for (int j = 0; j < 4; ++j)
        Lg[(((lane>>4)<<2) + j)*132 + wn*32 + cf*16 + r0] = acc[cf][j];
    }
    __syncthreads();                                 // B2: gates ready
    // ---- LSTM cell (k-half reduction + bias + nonlinearities), c in regs ----
    if (tid < 256){
      f32x4 gA = *(const f32x4*)(Lg0 + er*132 + 8*up);
      f32x4 gB = *(const f32x4*)(Lg0 + er*132 + 8*up + 4);
      f32x4 hA = *(const f32x4*)(Lg1 + er*132 + 8*up);
      f32x4 hB = *(const f32x4*)(Lg1 + er*132 + 8*up + 4);
      if (t){ gA = gA + hA + b1qA; gB = gB + hB + b1qB; }
      else {
        gA = gA + hA + *(const f32x4*)(bias0 + gw*128 + 8*up);
        gB = gB + hB + *(const f32x4*)(bias0 + gw*128 + 8*up + 4);
      }
      float I0 = 1.f/(1.f+__expf(-gA[0])), F0 = 1.f/(1.f+__expf(-gA[1]));
      float G0 = tanhf(gA[2]),             O0 = 1.f/(1.f+__expf(-gA[3]));
      float I1 = 1.f/(1.f+__expf(-gB[0])), F1 = 1.f/(1.f+__expf(-gB[1]));
      float G1 = tanhf(gB[2]),             O1 = 1.f/(1.f+__expf(-gB[3]));
      cA = F0*cA + I0*G0;  float h0v = O0*tanhf(cA);
      cB = F1*cB + I1*G1;  float h1v = O1*tanhf(cB);
      unsigned pk = pack2h(h0v, h1v);
      // h store = write-through to IC (fresh address Hh[t])
      short* pa = Hh + (size_t)t*262144 + (size_t)grow*1024 + posE;
      asm volatile("global_store_dword %0, %1, off sc0 sc1" :: "v"(pa), "v"(pk));
    }
    vm0();                                           // own stores at coherence point
    if (t < 127){
      __syncthreads();                               // B3: whole WG's h is out
      if (tid == 0){
        unsigned val = (unsigned)(t+1);
        unsigned* fp = flagC + gw;
        asm volatile("global_store_dword %0, %1, off sc0 sc1" :: "v"(fp), "v"(val) : "memory");
      }
      if (wv == 0){
        const unsigned* pp = flagC + (size_t)lane*4; // lanes 0..7 cover 32 flags
        unsigned tgt = (unsigned)(t+1);
        while (true){
          u32x4 f;
          asm volatile("global_load_dwordx4 %0, %1, off sc0 sc1\n\ts_waitcnt vmcnt(0)"
                       : "=v"(f) : "v"(pp) : "memory");
          bool ok = (lane >= 8) || (f[0] >= tgt && f[1] >= tgt && f[2] >= tgt && f[3] >= tgt);
          if (__all(ok)) break;
        }
      }
      __syncthreads();                               // B4: safe to stage next step
    }
  }
}

// ---------------- final Y GEMM ----------------
// out[b][t][o] = Hh[t*256+b] . owB[o] + out_b[o] ; tile 128x256, 8 waves
__global__ __launch_bounds__(512) void k_y(const short* __restrict__ Hh,
                                           const short* __restrict__ owB,
                                           const float* __restrict__ out_b,
                                           float* __restrict__ out){
  __shared__ __align__(16) short As[2*8192];    // [128][64] x2
  __shared__ __align__(16) short Bs[2*16384];   // [256][64] x2
  int tid = threadIdx.x, lane = tid & 63, wv = tid >> 6;
  int wr = (wv>>2)*64, wc = (wv&3)*64;
  size_t Rm = (size_t)blockIdx.x * 128;
  const short* Ab = Hh + Rm*1024;
  f32x4 acc[4][4] = {};
  auto stA = [&](int c, short* dst){
#pragma unroll
    for (int jj = 0; jj < 2; ++jj){ int j = wv*2 + jj;
      gll16(Ab + (size_t)(j*8 + (lane>>3))*1024 + c*64 + (lane&7)*8, dst + j*512); }
  };
  auto stB = [&](int c, short* dst){
#pragma unroll
    for (int jj = 0; jj < 4; ++jj){ int j = wv*4 + jj;
      gll16(owB + (size_t)(j*8 + (lane>>3))*1024 + c*64 + (lane&7)*8, dst + j*512); }
  };
  stA(0, As); stB(0, Bs);
  __syncthreads();
  int buf = 0;
  for (int c = 0; c < 16; ++c){
    if (c+1 < 16){ stA(c+1, As + (buf^1)*8192); stB(c+1, Bs + (buf^1)*16384); }
    const short* At = As + buf*8192;
    const short* Bt = Bs + buf*16384;
#pragma unroll
    for (int kk = 0; kk < 2; ++kk){
      f16x8 av[4], bv[4];
#pragma unroll
      for (int mi = 0; mi < 4; ++mi) av[mi] = fragh(At, wr + mi*16, kk, lane);
#pragma unroll
      for (int ni = 0; ni < 4; ++ni) bv[ni] = fragh(Bt, wc + ni*16, kk, lane);
#pragma unroll
      for (int mi = 0; mi < 4; ++mi)
#pragma unroll
      for (int ni = 0; ni < 4; ++ni) acc[mi][ni] = MFMA16(av[mi], bv[ni], acc[mi][ni]);
    }
    __syncthreads();
    buf ^= 1;
  }
#pragma unroll
  for (int ni = 0; ni < 4; ++ni){
    int col = wc + ni*16 + (lane & 15);
    float bv = out_b[col];
#pragma unroll
    for (int mi = 0; mi < 4; ++mi)
#pragma unroll
    for (int r = 0; r < 4; ++r){
      size_t m = Rm + wr + mi*16 + ((lane>>4)<<2) + r;
      int t = (int)(m >> 8), bb = (int)(m & 255);
      out[(size_t)bb*32768 + (size_t)t*256 + col] = acc[mi][ni][r] + bv;
    }
  }
}

extern "C" void kernel_launch(void* const* d_in, const int* in_sizes, int n_in,
                              void* d_out, int out_size, void* d_ws, size_t ws_size,
                              hipStream_t stream) {
  (void)in_sizes; (void)n_in; (void)out_size; (void)ws_size;
  const float* latent = (const float*)d_in[0];
  const float* fc_W   = (const float*)d_in[1];
  const float* fc_b   = (const float*)d_in[2];
  const float* W_ih   = (const float*)d_in[3];
  const float* W_hh   = (const float*)d_in[4];
  const float* b_ih   = (const float*)d_in[5];
  const float* b_hh   = (const float*)d_in[6];
  const float* out_W  = (const float*)d_in[7];
  const float* out_b  = (const float*)d_in[8];
  float* out = (float*)d_out;
  char*  ws  = (char*)d_ws;
  const size_t MB = 1u << 20;
  short* WtF   = (short*)(ws + 0);               //  8 MB W_total fp16 frag blocks
  short* W0F   = (short*)(ws + 8*MB);            //  8 MB W_hh   fp16 frag blocks
  short* A0    = (short*)(ws + 16*MB);           // 512 KB h0 fp16 [256][1024] swz
  float* bias0 = (float*)(ws + 17*MB);           //  16 KB permuted
  float* bias1 = (float*)(ws + 17*MB + 65536);   //  16 KB permuted
  short* owB   = (short*)(ws + 17*MB + 131072);  // 512 KB out_W fp16 swz
  short* WihF  = (short*)(ws + 18*MB);           //   2 MB W_ih fp16 swz
  short* owT   = (short*)(ws + 20*MB);           // 512 KB out_W^T fp16 swz
  short* latF  = (short*)(ws + 20*MB + 524288);  // 256 KB latent fp16 swz
  short* fcwF  = (short*)(ws + 21*MB);           //   1 MB fc_W fp16 swz
  unsigned* flg= (unsigned*)(ws + 22*MB);        //  32 KB flags
  short* Hh    = (short*)(ws + 23*MB);           //  64 MB h history fp16 swz

  k_prep<<<1024, 256, 0, stream>>>(W_ih, out_W, latent, fc_W, W_hh, b_ih, b_hh,
                                   WihF, owT, owB, latF, fcwF, W0F, bias0, flg);
  k_bias1<<<16, 256, 0, stream>>>(W_ih, out_b, bias0, bias1);
  k_wtotal<<<dim3(64,16), 256, 0, stream>>>(WihF, owT, W_hh, WtF);
  k_h0<<<dim3(4,16), 256, 0, stream>>>(latF, fcwF, fc_b, A0);
  k_persist<<<512, 512, 0, stream>>>(WtF, W0F, bias0, bias1, A0, Hh, flg);
  k_y<<<256, 512, 0, stream>>>(Hh, owB, out_b, out);
}

// Round 12
// 649.403 us; speedup vs baseline: 1.8683x; 1.8683x over previous
//
#include <hip/hip_runtime.h>

// Decoder: h0 = latent@fc_W^T + fc_b ; 128-step LSTM with folded feedback
// (x_t = y_{t-1} folded into W_total = W_hh + W_ih@out_W) ; Y = H_hist@out_W^T + out_b.
// All fp16. k_persist runs ALL 128 steps: 8 chains of 32 batch rows, 32 WGs/chain.
// FINAL (revert to round-4 best, 649.75us): weights in Breg (compiler streams from
// L2 at the 128-VGPR cap — measured equivalent to resident), A staged coalesced
// sc0+sc1 -> LDS per step, c-state in registers, kh-half split via LDS fp32
// partials, WG flag + wave0 dwordx4 poll. All cross-WG data/flags sc0+sc1 (device
// coherence point). 11-round ledger: 5 structural variants (direct-frags, per-wave
// flags, L2-scope sync, data-as-flag, 2WG/CU co-location) all regressed or hung;
// this protocol is the measured latency floor (~4.7us/step).
// Row-major fp16 ws matrices are "swz": elem (row,k) stored at k ^ ((row&7)<<3).

typedef __attribute__((ext_vector_type(8))) _Float16 f16x8;
typedef __attribute__((ext_vector_type(4))) float f32x4;
typedef __attribute__((ext_vector_type(4))) unsigned u32x4;

#define MFMA16(a,b,c) __builtin_amdgcn_mfma_f32_16x16x32_f16(a,b,c,0,0,0)

__device__ __forceinline__ short f2h(float x){
  return __builtin_bit_cast(short, (_Float16)x);
}
__device__ __forceinline__ unsigned pack2h(float a, float b){
  unsigned short ua = __builtin_bit_cast(unsigned short, (_Float16)a);
  unsigned short ub = __builtin_bit_cast(unsigned short, (_Float16)b);
  return (unsigned)ua | ((unsigned)ub << 16);
}

__device__ __forceinline__ void gll16(const void* g, void* l){
  __builtin_amdgcn_global_load_lds((const __attribute__((address_space(1))) void*)g,
                                   (__attribute__((address_space(3))) void*)l, 16, 0, 0);
}

// stage a 64x64 fp16 tile (pre-swizzled global, row-major ld=ldk) into LDS (linear image)
__device__ __forceinline__ void stage_t(const short* gRC, int ldk, short* lds, int lane, int wv){
#pragma unroll
  for (int jj = 0; jj < 2; ++jj){
    int j = wv*2 + jj;
    const short* src = gRC + (size_t)(j*8 + (lane>>3))*ldk + ((lane&7)*8);
    gll16(src, lds + j*512);
  }
}

// MFMA A/B fragment from a 64x64 swizzled LDS tile image
__device__ __forceinline__ f16x8 fragh(const short* t, int r, int kk, int lane){
  int row = r + (lane & 15);
  int k0  = (kk<<5) + ((lane>>4)<<3);
  return *(const f16x8*)(t + row*64 + (k0 ^ ((row & 7)<<3)));
}

// generic 64x64-tile fp16 GEMM core, CH k-chunks of 64
template<int CH>
__device__ __forceinline__ void core_k(const short* Ag, const short* Bg, int ldk,
                                       short* As, short* Bs, f32x4 (&acc)[2][2],
                                       int lane, int wv, int wr, int wc){
  stage_t(Ag, ldk, As, lane, wv);
  stage_t(Bg, ldk, Bs, lane, wv);
  __syncthreads();
  int buf = 0;
  for (int c = 0; c < CH; ++c){
    if (c+1 < CH){
      stage_t(Ag + (c+1)*64, ldk, As + (buf^1)*4096, lane, wv);
      stage_t(Bg + (c+1)*64, ldk, Bs + (buf^1)*4096, lane, wv);
    }
    const short* At = As + buf*4096;
    const short* Bt = Bs + buf*4096;
#pragma unroll
    for (int kk = 0; kk < 2; ++kk){
      f16x8 a0 = fragh(At, wr,    kk, lane), a1 = fragh(At, wr+16, kk, lane);
      f16x8 b0 = fragh(Bt, wc,    kk, lane), b1 = fragh(Bt, wc+16, kk, lane);
      acc[0][0] = MFMA16(a0,b0,acc[0][0]); acc[0][1] = MFMA16(a0,b1,acc[0][1]);
      acc[1][0] = MFMA16(a1,b0,acc[1][0]); acc[1][1] = MFMA16(a1,b1,acc[1][1]);
    }
    __syncthreads();
    buf ^= 1;
  }
}

// ---------------- setup ----------------
// Weight frag-block layout: block(c,s) = 512 shorts at ((c*32)+s)*512 ; within:
// lane l covers (gatecol p = 16c + (l&15), k = 32s + (l>>4)*8 .. +8). p is the
// PERMUTED gate index p = ((r&1023)<<2) | (r>>10) (unit*4+gate, torch i,f,g,o).

__global__ void k_prep(const float* __restrict__ W_ih, const float* __restrict__ out_W,
                       const float* __restrict__ latent, const float* __restrict__ fc_W,
                       const float* __restrict__ W_hh,
                       const float* __restrict__ b_ih, const float* __restrict__ b_hh,
                       short* __restrict__ WihF, short* __restrict__ owT,
                       short* __restrict__ owB, short* __restrict__ latF,
                       short* __restrict__ fcwF, short* __restrict__ W0F,
                       float* __restrict__ bias0, unsigned* __restrict__ flags){
  int T = blockDim.x*gridDim.x, t0 = blockIdx.x*blockDim.x + threadIdx.x;
  for (int i = t0; i < 8192; i += T) flags[i] = 0u;
  for (int idx = t0; idx < 4096*256; idx += T){    // WihF [4096][256] swz
    int r = idx >> 8, j = idx & 255;
    WihF[(size_t)r*256 + (j ^ ((r&7)<<3))] = f2h(W_ih[idx]);
  }
  for (int idx = t0; idx < 1024*256; idx += T){    // owT [1024][256]: owT[c][j]=out_W[j][c]
    int c = idx >> 8, j = idx & 255;
    owT[(size_t)c*256 + (j ^ ((c&7)<<3))] = f2h(out_W[(size_t)j*1024 + c]);
  }
  for (int idx = t0; idx < 256*1024; idx += T){    // owB [256][1024] swz
    int o = idx >> 10, k = idx & 1023;
    owB[(size_t)o*1024 + (k ^ ((o&7)<<3))] = f2h(out_W[idx]);
  }
  for (int idx = t0; idx < 256*512; idx += T){     // latF [256][512] swz
    int b = idx >> 9, j = idx & 511;
    latF[(size_t)b*512 + (j ^ ((b&7)<<3))] = f2h(latent[idx]);
  }
  for (int idx = t0; idx < 1024*512; idx += T){    // fcwF [1024][512] swz
    int n = idx >> 9, j = idx & 511;
    fcwF[(size_t)n*512 + (j ^ ((n&7)<<3))] = f2h(fc_W[idx]);
  }
  for (int idx = t0; idx < 4096*1024; idx += T){   // W0F = fp16(W_hh) frag blocks
    int r = idx >> 10, k = idx & 1023;
    int p = ((r & 1023)<<2) | (r >> 10);
    size_t a = ((size_t)(p>>4)*32 + (k>>5))*512 + ((size_t)((((k>>3)&3)<<4)|(p&15)))*8 + (k&7);
    W0F[a] = f2h(W_hh[idx]);
  }
  for (int r = t0; r < 4096; r += T){
    int rp = ((r & 1023)<<2) | (r >> 10);
    bias0[rp] = b_ih[r] + b_hh[r];
  }
}

__global__ void k_bias1(const float* __restrict__ W_ih, const float* __restrict__ out_b,
                        const float* __restrict__ bias0, float* __restrict__ bias1){
  int r = blockIdx.x*256 + threadIdx.x;            // 4096 threads
  float s = 0.f;
  for (int j = 0; j < 256; ++j) s += W_ih[(size_t)r*256 + j]*out_b[j];
  int rp = ((r & 1023)<<2) | (r >> 10);
  bias1[rp] = bias0[rp] + s;
}

// WtF = fp16(W_hh + W_ih@out_W), frag-block layout
__global__ __launch_bounds__(256) void k_wtotal(const short* __restrict__ WihF,
                                                const short* __restrict__ owT,
                                                const float* __restrict__ W_hh,
                                                short* __restrict__ WtF){
  __shared__ __align__(16) short As[2*4096];
  __shared__ __align__(16) short Bs[2*4096];
  int tid = threadIdx.x, lane = tid & 63, wv = tid >> 6;
  int wr = (wv>>1)*32, wc = (wv&1)*32;
  int Rm = blockIdx.x*64, Rn = blockIdx.y*64;
  f32x4 acc[2][2] = {};
  core_k<4>(WihF + (size_t)Rm*256, owT + (size_t)Rn*256, 256, As, Bs, acc, lane, wv, wr, wc);
#pragma unroll
  for (int mi = 0; mi < 2; ++mi)
#pragma unroll
  for (int ni = 0; ni < 2; ++ni)
#pragma unroll
  for (int r = 0; r < 4; ++r){
    int row = Rm + wr + mi*16 + ((lane>>4)<<2) + r;   // gate row
    int col = Rn + wc + ni*16 + (lane & 15);          // k
    float v = acc[mi][ni][r] + W_hh[(size_t)row*1024 + col];
    int p = ((row & 1023)<<2) | (row >> 10);
    size_t a = ((size_t)(p>>4)*32 + (col>>5))*512 + ((size_t)((((col>>3)&3)<<4)|(p&15)))*8 + (col&7);
    WtF[a] = f2h(v);
  }
}

// h0 = latent@fc_W^T + fc_b -> A0 fp16 swz
__global__ __launch_bounds__(256) void k_h0(const short* __restrict__ latF,
                                            const short* __restrict__ fcwF,
                                            const float* __restrict__ fc_b,
                                            short* __restrict__ A0){
  __shared__ __align__(16) short As[2*4096];
  __shared__ __align__(16) short Bs[2*4096];
  int tid = threadIdx.x, lane = tid & 63, wv = tid >> 6;
  int wr = (wv>>1)*32, wc = (wv&1)*32;
  int Rm = blockIdx.x*64, Rn = blockIdx.y*64;
  f32x4 acc[2][2] = {};
  core_k<8>(latF + (size_t)Rm*512, fcwF + (size_t)Rn*512, 512, As, Bs, acc, lane, wv, wr, wc);
#pragma unroll
  for (int mi = 0; mi < 2; ++mi)
#pragma unroll
  for (int ni = 0; ni < 2; ++ni)
#pragma unroll
  for (int r = 0; r < 4; ++r){
    int row = Rm + wr + mi*16 + ((lane>>4)<<2) + r;   // batch
    int col = Rn + wc + ni*16 + (lane & 15);          // unit
    float h = acc[mi][ni][r] + fc_b[col];
    A0[(size_t)row*1024 + (col ^ ((row&7)<<3))] = f2h(h);
  }
}

// ---------------- persistent kernel: steps 0..127 ----------------
// 256 WGs x 512 thr. chain = wg&7, gw = wg>>3. WG: batch rows chain*32..+32,
// permuted gate cols gw*128..+128. Wave (wn=wv&3, kh=wv>>2): cols wn*32..+32,
// k-half kh*512..+512.
__global__ __launch_bounds__(512, 2) void k_persist(
    const short* __restrict__ WtF, const short* __restrict__ W0F,
    const float* __restrict__ bias0, const float* __restrict__ bias1,
    short* __restrict__ A0, short* __restrict__ A1, short* __restrict__ Hh,
    unsigned* __restrict__ flags){
  __shared__ __align__(16) short Asl[32*1024];      // 64 KB chain A slice (swz image)
  __shared__ __align__(16) float Lg0[32*132];       // kh=0 partial gates
  __shared__ __align__(16) float Lg1[32*132];       // kh=1 partial gates
  const int tid = threadIdx.x, lane = tid & 63, wv = tid >> 6;
  const int wg = blockIdx.x;
  const int chain = wg & 7, gw = wg >> 3;
  const int wn = wv & 3, kh = wv >> 2;
  const int cbase = gw*8 + wn*2, sbase = kh*16;

  // W_total fragments (128 VGPRs; compiler streams from L2 at the cap — measured ok)
  f16x8 Breg[2][16];
  {
    const short* src = WtF + ((size_t)cbase*32 + sbase)*512 + lane*8;
#pragma unroll
    for (int cf = 0; cf < 2; ++cf)
#pragma unroll
      for (int s = 0; s < 16; ++s)
        Breg[cf][s] = *(const f16x8*)(src + (size_t)(cf*32 + s)*512);
  }
  const short* W0base = W0F + ((size_t)cbase*32 + sbase)*512 + lane*8;

  // A-frag addressing
  const int r0 = lane & 15;
  const int kql = (lane>>4)<<3;
  const int sw = (r0 & 7) << 3;

  // cell phase: thread (er,up) owns row er, units 2up,2up+1 of this WG
  const int er = tid >> 4, up = tid & 15;
  const int grow = chain*32 + er;
  const int swE = (grow & 7) << 3;
  const int posE = (gw*32 + 2*up) ^ swE;            // pair stays adjacent, 4B aligned
  const f32x4 b1qA = *(const f32x4*)(bias1 + gw*128 + 8*up);
  const f32x4 b1qB = *(const f32x4*)(bias1 + gw*128 + 8*up + 4);
  float cA = 0.f, cB = 0.f;

  unsigned* flagC = flags + (size_t)chain*64;       // this chain's 32-flag line (128B)

  for (int t = 0; t < 128; ++t){
    const short* Ain = (t & 1) ? A1 : A0;
    short* Aout = (t & 1) ? A0 : A1;

    // ---- stage chain A slice: 8 coherent dwordx4 loads/lane -> LDS ----
    {
      u32x4 stg[8];
      const short* base = Ain + (size_t)(chain*32)*1024;
#pragma unroll
      for (int q = 0; q < 8; ++q){
        int i = wv*8 + q;
        const short* src = base + (size_t)(i>>1)*1024 + (i&1)*512 + lane*8;
        asm volatile("global_load_dwordx4 %0, %1, off sc0 sc1"
                     : "=v"(stg[q]) : "v"(src));
      }
      asm volatile("s_waitcnt vmcnt(0)" ::: "memory");
#pragma unroll
      for (int q = 0; q < 8; ++q){
        int i = wv*8 + q;
        *(u32x4*)((char*)Asl + (size_t)i*1024 + (size_t)lane*16) = stg[q];
      }
    }
    __syncthreads();

    f32x4 acc[2][2] = {};
    const short* Ar0 = Asl + r0*1024;
    const short* Ar1 = Asl + (16 + r0)*1024;
    if (t == 0){
#pragma unroll
      for (int s = 0; s < 16; ++s){
        int k = (sbase + s)*32 + kql;
        f16x8 w0 = *(const f16x8*)(W0base + (size_t)(0*32 + s)*512);
        f16x8 w1 = *(const f16x8*)(W0base + (size_t)(1*32 + s)*512);
        f16x8 a0 = *(const f16x8*)(Ar0 + (k ^ sw));
        f16x8 a1 = *(const f16x8*)(Ar1 + (k ^ sw));
        acc[0][0] = MFMA16(a0, w0, acc[0][0]);
        acc[0][1] = MFMA16(a0, w1, acc[0][1]);
        acc[1][0] = MFMA16(a1, w0, acc[1][0]);
        acc[1][1] = MFMA16(a1, w1, acc[1][1]);
      }
    } else {
#pragma unroll
      for (int s = 0; s < 16; ++s){
        int k = (sbase + s)*32 + kql;
        f16x8 a0 = *(const f16x8*)(Ar0 + (k ^ sw));
        f16x8 a1 = *(const f16x8*)(Ar1 + (k ^ sw));
        acc[0][0] = MFMA16(a0, Breg[0][s], acc[0][0]);
        acc[0][1] = MFMA16(a0, Breg[1][s], acc[0][1]);
        acc[1][0] = MFMA16(a1, Breg[0][s], acc[1][0]);
        acc[1][1] = MFMA16(a1, Breg[1][s], acc[1][1]);
      }
    }
    // ---- partial gates -> LDS (kh halves in Lg0/Lg1) ----
    {
      float* Lg = kh ? Lg1 : Lg0;
#pragma unroll
      for (int rf = 0; rf < 2; ++rf)
#pragma unroll
      for (int cf = 0; cf < 2; ++cf)
#pragma unroll
      for (int j = 0; j < 4; ++j)
        Lg[(rf*16 + ((lane>>4)<<2) + j)*132 + wn*32 + cf*16 + r0] = acc[rf][cf][j];
    }
    __syncthreads();
    // ---- LSTM cell (k-half reduction + bias + nonlinearities), c in regs ----
    {
      f32x4 gA = *(const f32x4*)(Lg0 + er*132 + 8*up);
      f32x4 gB = *(const f32x4*)(Lg0 + er*132 + 8*up + 4);
      f32x4 hA = *(const f32x4*)(Lg1 + er*132 + 8*up);
      f32x4 hB = *(const f32x4*)(Lg1 + er*132 + 8*up + 4);
      if (t){ gA = gA + hA + b1qA; gB = gB + hB + b1qB; }
      else {
        gA = gA + hA + *(const f32x4*)(bias0 + gw*128 + 8*up);
        gB = gB + hB + *(const f32x4*)(bias0 + gw*128 + 8*up + 4);
      }
      float I0 = 1.f/(1.f+__expf(-gA[0])), F0 = 1.f/(1.f+__expf(-gA[1]));
      float G0 = tanhf(gA[2]),             O0 = 1.f/(1.f+__expf(-gA[3]));
      float I1 = 1.f/(1.f+__expf(-gB[0])), F1 = 1.f/(1.f+__expf(-gB[1]));
      float G1 = tanhf(gB[2]),             O1 = 1.f/(1.f+__expf(-gB[3]));
      cA = F0*cA + I0*G0;  float h0v = O0*tanhf(cA);
      cB = F1*cB + I1*G1;  float h1v = O1*tanhf(cB);
      unsigned pk = pack2h(h0v, h1v);
      short* pa = Aout + (size_t)grow*1024 + posE;
      asm volatile("global_store_dword %0, %1, off sc0 sc1" :: "v"(pa), "v"(pk));
      *(unsigned*)(Hh + (size_t)t*262144 + (size_t)grow*1024 + posE) = pk;  // plain
      asm volatile("s_waitcnt vmcnt(0)" ::: "memory");   // own stores at coherence point
    }
    if (t < 127){
      __syncthreads();                                   // whole WG's h is out
      if (tid == 0){
        unsigned val = (unsigned)(t+1);
        unsigned* fp = flagC + gw;
        asm volatile("global_store_dword %0, %1, off sc0 sc1" :: "v"(fp), "v"(val) : "memory");
      }
      if (wv == 0){
        const unsigned* pp = flagC + (size_t)lane*4;     // lanes 0..7 cover 32 flags
        unsigned tgt = (unsigned)(t+1);
        while (true){
          u32x4 f;
          asm volatile("global_load_dwordx4 %0, %1, off sc0 sc1\n\ts_waitcnt vmcnt(0)"
                       : "=v"(f) : "v"(pp) : "memory");
          bool ok = (lane >= 8) || (f[0] >= tgt && f[1] >= tgt && f[2] >= tgt && f[3] >= tgt);
          if (__all(ok)) break;
        }
      }
      __syncthreads();
    }
  }
}

// ---------------- final Y GEMM ----------------
// out[b][t][o] = Hh[t*256+b] . owB[o] + out_b[o] ; tile 128x256, 8 waves
__global__ __launch_bounds__(512) void k_y(const short* __restrict__ Hh,
                                           const short* __restrict__ owB,
                                           const float* __restrict__ out_b,
                                           float* __restrict__ out){
  __shared__ __align__(16) short As[2*8192];    // [128][64] x2
  __shared__ __align__(16) short Bs[2*16384];   // [256][64] x2
  int tid = threadIdx.x, lane = tid & 63, wv = tid >> 6;
  int wr = (wv>>2)*64, wc = (wv&3)*64;
  size_t Rm = (size_t)blockIdx.x * 128;
  const short* Ab = Hh + Rm*1024;
  f32x4 acc[4][4] = {};
  auto stA = [&](int c, short* dst){
#pragma unroll
    for (int jj = 0; jj < 2; ++jj){ int j = wv*2 + jj;
      gll16(Ab + (size_t)(j*8 + (lane>>3))*1024 + c*64 + (lane&7)*8, dst + j*512); }
  };
  auto stB = [&](int c, short* dst){
#pragma unroll
    for (int jj = 0; jj < 4; ++jj){ int j = wv*4 + jj;
      gll16(owB + (size_t)(j*8 + (lane>>3))*1024 + c*64 + (lane&7)*8, dst + j*512); }
  };
  stA(0, As); stB(0, Bs);
  __syncthreads();
  int buf = 0;
  for (int c = 0; c < 16; ++c){
    if (c+1 < 16){ stA(c+1, As + (buf^1)*8192); stB(c+1, Bs + (buf^1)*16384); }
    const short* At = As + buf*8192;
    const short* Bt = Bs + buf*16384;
#pragma unroll
    for (int kk = 0; kk < 2; ++kk){
      f16x8 av[4], bv[4];
#pragma unroll
      for (int mi = 0; mi < 4; ++mi) av[mi] = fragh(At, wr + mi*16, kk, lane);
#pragma unroll
      for (int ni = 0; ni < 4; ++ni) bv[ni] = fragh(Bt, wc + ni*16, kk, lane);
#pragma unroll
      for (int mi = 0; mi < 4; ++mi)
#pragma unroll
      for (int ni = 0; ni < 4; ++ni) acc[mi][ni] = MFMA16(av[mi], bv[ni], acc[mi][ni]);
    }
    __syncthreads();
    buf ^= 1;
  }
#pragma unroll
  for (int ni = 0; ni < 4; ++ni){
    int col = wc + ni*16 + (lane & 15);
    float bv = out_b[col];
#pragma unroll
    for (int mi = 0; mi < 4; ++mi)
#pragma unroll
    for (int r = 0; r < 4; ++r){
      size_t m = Rm + wr + mi*16 + ((lane>>4)<<2) + r;
      int t = (int)(m >> 8), bb = (int)(m & 255);
      out[(size_t)bb*32768 + (size_t)t*256 + col] = acc[mi][ni][r] + bv;
    }
  }
}

extern "C" void kernel_launch(void* const* d_in, const int* in_sizes, int n_in,
                              void* d_out, int out_size, void* d_ws, size_t ws_size,
                              hipStream_t stream) {
  (void)in_sizes; (void)n_in; (void)out_size; (void)ws_size;
  const float* latent = (const float*)d_in[0];
  const float* fc_W   = (const float*)d_in[1];
  const float* fc_b   = (const float*)d_in[2];
  const float* W_ih   = (const float*)d_in[3];
  const float* W_hh   = (const float*)d_in[4];
  const float* b_ih   = (const float*)d_in[5];
  const float* b_hh   = (const float*)d_in[6];
  const float* out_W  = (const float*)d_in[7];
  const float* out_b  = (const float*)d_in[8];
  float* out = (float*)d_out;
  char*  ws  = (char*)d_ws;
  const size_t MB = 1u << 20;
  short* WtF   = (short*)(ws + 0);               //  8 MB W_total fp16 frag blocks
  short* W0F   = (short*)(ws + 8*MB);            //  8 MB W_hh   fp16 frag blocks
  short* A0    = (short*)(ws + 16*MB);           // 512 KB h fp16 [256][1024] swz
  short* A1    = (short*)(ws + 16*MB + 524288);  // 512 KB
  float* bias0 = (float*)(ws + 17*MB);           //  16 KB permuted
  float* bias1 = (float*)(ws + 17*MB + 65536);   //  16 KB permuted
  short* owB   = (short*)(ws + 17*MB + 131072);  // 512 KB out_W fp16 swz
  short* WihF  = (short*)(ws + 18*MB);           //   2 MB W_ih fp16 swz
  short* owT   = (short*)(ws + 20*MB);           // 512 KB out_W^T fp16 swz
  short* latF  = (short*)(ws + 20*MB + 524288);  // 256 KB latent fp16 swz
  short* fcwF  = (short*)(ws + 21*MB);           //   1 MB fc_W fp16 swz
  unsigned* flg= (unsigned*)(ws + 22*MB);        //  32 KB flags
  short* Hh    = (short*)(ws + 23*MB);           //  64 MB h history fp16 swz

  k_prep<<<1024, 256, 0, stream>>>(W_ih, out_W, latent, fc_W, W_hh, b_ih, b_hh,
                                   WihF, owT, owB, latF, fcwF, W0F, bias0, flg);
  k_bias1<<<16, 256, 0, stream>>>(W_ih, out_b, bias0, bias1);
  k_wtotal<<<dim3(64,16), 256, 0, stream>>>(WihF, owT, W_hh, WtF);
  k_h0<<<dim3(4,16), 256, 0, stream>>>(latF, fcwF, fc_b, A0);
  k_persist<<<256, 512, 0, stream>>>(WtF, W0F, bias0, bias1, A0, A1, Hh, flg);
  k_y<<<256, 512, 0, stream>>>(Hh, owB, out_b, out);
}